// Round 3
// baseline (202.158 us; speedup 1.0000x reference)
//
#include <hip/hip_runtime.h>
#include <cstdint>
#include <math.h>

// Problem constants
#define B_ROWS 16384
#define SEQ_L  200
#define EMBED  16
#define HIDDEN 64
#define TICKS  10
#define NELEM  1048576   // B*H

// ---------------- threefry2x32 (jax), bit-exact ----------------
__device__ __forceinline__ uint32_t rotl32(uint32_t v, int r) {
  return (v << r) | (v >> (32 - r));
}

__device__ __forceinline__ void tf2x32(uint32_t k0, uint32_t k1,
                                       uint32_t x0, uint32_t x1,
                                       uint32_t& o0, uint32_t& o1) {
  uint32_t ks2 = k0 ^ k1 ^ 0x1BD11BDAu;
  x0 += k0; x1 += k1;
  x0 += x1; x1 = rotl32(x1, 13); x1 ^= x0;
  x0 += x1; x1 = rotl32(x1, 15); x1 ^= x0;
  x0 += x1; x1 = rotl32(x1, 26); x1 ^= x0;
  x0 += x1; x1 = rotl32(x1, 6);  x1 ^= x0;
  x0 += k1; x1 += ks2 + 1u;
  x0 += x1; x1 = rotl32(x1, 17); x1 ^= x0;
  x0 += x1; x1 = rotl32(x1, 29); x1 ^= x0;
  x0 += x1; x1 = rotl32(x1, 16); x1 ^= x0;
  x0 += x1; x1 = rotl32(x1, 24); x1 ^= x0;
  x0 += ks2; x1 += k0 + 2u;
  x0 += x1; x1 = rotl32(x1, 13); x1 ^= x0;
  x0 += x1; x1 = rotl32(x1, 15); x1 ^= x0;
  x0 += x1; x1 = rotl32(x1, 26); x1 ^= x0;
  x0 += x1; x1 = rotl32(x1, 6);  x1 ^= x0;
  x0 += k0; x1 += k1 + 3u;
  x0 += x1; x1 = rotl32(x1, 17); x1 ^= x0;
  x0 += x1; x1 = rotl32(x1, 29); x1 ^= x0;
  x0 += x1; x1 = rotl32(x1, 16); x1 ^= x0;
  x0 += x1; x1 = rotl32(x1, 24); x1 ^= x0;
  x0 += k1; x1 += ks2 + 4u;
  x0 += x1; x1 = rotl32(x1, 13); x1 ^= x0;
  x0 += x1; x1 = rotl32(x1, 15); x1 ^= x0;
  x0 += x1; x1 = rotl32(x1, 26); x1 ^= x0;
  x0 += x1; x1 = rotl32(x1, 6);  x1 ^= x0;
  o0 = x0 + ks2;
  o1 = x1 + k0 + 5u;
}

// Partitionable random_bits, 32-bit: xor-fold of the two outputs,
// counter = (hi32(idx)=0, lo32(idx)=idx) for idx < 2^32.
__device__ __forceinline__ uint32_t tf_fold(uint32_t k0, uint32_t k1,
                                            uint32_t idx) {
  uint32_t o0, o1;
  tf2x32(k0, k1, 0u, idx, o0, o1);
  return o0 ^ o1;
}

// Correctly-rounded f32 log via double log (emulates glibc logf, which is
// ~correctly rounded; double log rel err ~1e-16 -> same f32 rounding).
__device__ __forceinline__ float logf_cr(float t) {
  return (float)log((double)t);
}

// XLA log1p f32 (ElementalIrEmitter::EmitLog1p): |x|<1e-4 -> ((-0.5x)+1)*x,
// else log(x+1). Strict f32, no contraction.
__device__ __forceinline__ float log1p_f32_xla(float x) {
  if (fabsf(x) < 1e-4f) {
    return __fmul_rn(__fadd_rn(__fmul_rn(-0.5f, x), 1.0f), x);
  }
  return logf_cr(__fadd_rn(x, 1.0f));
}

// XLA chlo erf_inv f32 expansion: strict f32 mul/add (no fma contraction),
// Giles coefficients.
__device__ __forceinline__ float erfinv_f32_xla(float x) {
  float xx = __fmul_rn(x, x);
  float w = -log1p_f32_xla(-xx);
  float p;
  if (w < 5.0f) {
    float ww = __fsub_rn(w, 2.5f);
    p = 2.81022636e-08f;
    p = __fadd_rn(__fmul_rn(p, ww), 3.43273939e-07f);
    p = __fadd_rn(__fmul_rn(p, ww), -3.5233877e-06f);
    p = __fadd_rn(__fmul_rn(p, ww), -4.39150654e-06f);
    p = __fadd_rn(__fmul_rn(p, ww), 0.00021858087f);
    p = __fadd_rn(__fmul_rn(p, ww), -0.00125372503f);
    p = __fadd_rn(__fmul_rn(p, ww), -0.00417768164f);
    p = __fadd_rn(__fmul_rn(p, ww), 0.246640727f);
    p = __fadd_rn(__fmul_rn(p, ww), 1.50140941f);
  } else {
    float ww = __fsub_rn(__fsqrt_rn(w), 3.0f);
    p = -0.000200214257f;
    p = __fadd_rn(__fmul_rn(p, ww), 0.000100950558f);
    p = __fadd_rn(__fmul_rn(p, ww), 0.00134934322f);
    p = __fadd_rn(__fmul_rn(p, ww), -0.00367342844f);
    p = __fadd_rn(__fmul_rn(p, ww), 0.00573950773f);
    p = __fadd_rn(__fmul_rn(p, ww), -0.0076224613f);
    p = __fadd_rn(__fmul_rn(p, ww), 0.00943887047f);
    p = __fadd_rn(__fmul_rn(p, ww), 1.00167406f);
    p = __fadd_rn(__fmul_rn(p, ww), 2.83297682f);
  }
  return __fmul_rn(p, x);
}

// jax normal f32-exact: u = uniform(lo=nextafterf(-1,0), hi=1) bit pipeline;
// noise = 0.01f * (sqrt2_f32 * erfinv(u)). Strict f32.
__device__ __forceinline__ float noise_from_bits(uint32_t bits) {
  const float lo = __uint_as_float(0xBF7FFFFFu);        // -(1 - 2^-24)
  float f = __uint_as_float((bits >> 9) | 0x3f800000u); // [1,2)
  f = __fsub_rn(f, 1.0f);                               // [0,1), exact
  float u = __fadd_rn(__fmul_rn(f, 2.0f), lo);          // (hi-lo) rounds to 2.0f
  u = fmaxf(u, lo);
  float y = erfinv_f32_xla(u);
  float n = __fmul_rn(__uint_as_float(0x3FB504F3u), y); // sqrt(2) f32
  return __fmul_rn(0.01f, n);
}

// ------------- Kernel A: embedding gather + masked mean (f32, XLA order) ----
__global__ __launch_bounds__(256) void embed_mean_kernel(
    const int* __restrict__ tokens, const float* __restrict__ table,
    float* __restrict__ avg_emb) {
  __shared__ int s_tok[16 * SEQ_L];
  int tid = threadIdx.x;
  const int* gtok = tokens + (size_t)blockIdx.x * 16 * SEQ_L;
  for (int i = tid; i < 16 * SEQ_L; i += 256) s_tok[i] = gtok[i];
  __syncthreads();

  int r = tid >> 4, e = tid & 15;
  int b = blockIdx.x * 16 + r;
  const int* trow = s_tok + r * SEQ_L;
  float acc = 0.0f;
  int cnt = 0;
  for (int l = 0; l < SEQ_L; ++l) {
    int tok = trow[l];
    if (tok != 0) {
      acc = __fadd_rn(acc, table[(size_t)tok * EMBED + e]);
      cnt++;
    }
  }
  float valid = fmaxf((float)cnt, 1.0f);     // clip(mask.sum, 1.0)
  avg_emb[b * EMBED + e] = __fdiv_rn(acc, valid);
}

// ---- Kernel B: cortex recurrence, partitionable threefry (1 elem/thread),
//      strict f32, + fused readout (f64 wave butterfly) ---------------------
__global__ __launch_bounds__(256) void cortex_kernel(
    const float* __restrict__ avg_emb,
    const float* __restrict__ Wc, const float* __restrict__ bc,
    const float* __restrict__ Wr, const float* __restrict__ br,
    float* __restrict__ out) {
  // keys = split(key(1), 10) [foldlike]: keys[t] = tf((0,1), (0,t)) full pair.
  // kn,kf = split(keys[t], 2): kn = tf(keys[t],(0,0)), kf = tf(keys[t],(0,1)).
  __shared__ uint32_t s_kn0[TICKS], s_kn1[TICKS], s_kf0[TICKS], s_kf1[TICKS];
  if (threadIdx.x == 0) {
    for (int t = 0; t < TICKS; ++t) {
      uint32_t kt0, kt1;
      tf2x32(0u, 1u, 0u, (uint32_t)t, kt0, kt1);
      uint32_t a0, a1;
      tf2x32(kt0, kt1, 0u, 0u, a0, a1);
      s_kn0[t] = a0; s_kn1[t] = a1;
      tf2x32(kt0, kt1, 0u, 1u, a0, a1);
      s_kf0[t] = a0; s_kf1[t] = a1;
    }
  }
  __syncthreads();

  int j = blockIdx.x * 256 + threadIdx.x;   // 0..NELEM-1, = b*64 + h
  int h = j & 63;
  int b = j >> 6;

  // cur = avg_emb @ Wc^T + bc — FMA dot k ascending, then bias add.
  float wrow[EMBED];
  #pragma unroll
  for (int e = 0; e < EMBED; ++e) wrow[e] = Wc[h * EMBED + e];
  const float* ap = avg_emb + b * EMBED;
  float d = 0.0f;
  #pragma unroll
  for (int e = 0; e < EMBED; ++e) d = fmaf(ap[e], wrow[e], d);
  float cur = __fadd_rn(d, bc[h]);

  float v = 0.0f, rfr = 0.0f;
  int ac = 0;
  for (int t = 0; t < TICKS; ++t) {
    uint32_t nb = tf_fold(s_kn0[t], s_kn1[t], (uint32_t)j);
    uint32_t fb = tf_fold(s_kf0[t], s_kf1[t], (uint32_t)j);
    float z = noise_from_bits(nb);
    // v = ((v * 0.98f) + cur) + noise — strict f32
    v = __fadd_rn(__fadd_rn(__fmul_rn(v, 0.98f), cur), z);
    // fire = (v - refrac) > 0.5 && uniform >= 0.5 (MSB of fail bits)
    bool fire = (__fsub_rn(v, rfr) > 0.5f) && (fb >> 31);
    if (fire) v = 0.0f;
    rfr = __fadd_rn(__fmul_rn(rfr, 0.95f), fire ? 1.0f : 0.0f);
    ac += fire;
  }

  float s = __fdiv_rn((float)ac, 10.0f);

  // avg_spikes output (offset B*4), coalesced
  out[B_ROWS * 4 + j] = s;

  // logits = avg_spikes @ Wr^T + br — f64 butterfly over the wave's 64 h's
  // (one wave == one row b; tolerance covers order differences here).
  double pc[4];
  #pragma unroll
  for (int cc = 0; cc < 4; ++cc) pc[cc] = (double)s * (double)Wr[cc * HIDDEN + h];
  #pragma unroll
  for (int off = 32; off >= 1; off >>= 1) {
    #pragma unroll
    for (int cc = 0; cc < 4; ++cc) pc[cc] += __shfl_xor(pc[cc], off, 64);
  }
  if ((threadIdx.x & 63) == 0) {
    #pragma unroll
    for (int cc = 0; cc < 4; ++cc)
      out[b * 4 + cc] = (float)(pc[cc] + (double)br[cc]);
  }
}

extern "C" void kernel_launch(void* const* d_in, const int* in_sizes, int n_in,
                              void* d_out, int out_size, void* d_ws, size_t ws_size,
                              hipStream_t stream) {
  const int*   tokens = (const int*)d_in[0];
  const float* table  = (const float*)d_in[1];
  const float* Wc     = (const float*)d_in[2];
  const float* bc     = (const float*)d_in[3];
  const float* Wr     = (const float*)d_in[4];
  const float* br     = (const float*)d_in[5];
  float* out = (float*)d_out;
  float* avg = (float*)d_ws;   // B*EMBED f32 = 1 MB scratch

  embed_mean_kernel<<<B_ROWS / 16, 256, 0, stream>>>(tokens, table, avg);
  cortex_kernel<<<NELEM / 256, 256, 0, stream>>>(avg, Wc, bc, Wr, br, out);
}

// Round 5
// 168.157 us; speedup vs baseline: 1.2022x; 1.2022x over previous
//
#include <hip/hip_runtime.h>
#include <cstdint>
#include <math.h>

// Problem constants
#define B_ROWS 16384
#define SEQ_L  200
#define EMBED  16
#define HIDDEN 64
#define TICKS  10
#define NELEM  1048576   // B*H

// ---------------- threefry2x32 (jax partitionable), bit-exact ---------------
__device__ __forceinline__ uint32_t rotl32(uint32_t v, int r) {
  return (v << r) | (v >> (32 - r));
}

__device__ __forceinline__ void tf2x32(uint32_t k0, uint32_t k1,
                                       uint32_t x0, uint32_t x1,
                                       uint32_t& o0, uint32_t& o1) {
  uint32_t ks2 = k0 ^ k1 ^ 0x1BD11BDAu;
  x0 += k0; x1 += k1;
  x0 += x1; x1 = rotl32(x1, 13); x1 ^= x0;
  x0 += x1; x1 = rotl32(x1, 15); x1 ^= x0;
  x0 += x1; x1 = rotl32(x1, 26); x1 ^= x0;
  x0 += x1; x1 = rotl32(x1, 6);  x1 ^= x0;
  x0 += k1; x1 += ks2 + 1u;
  x0 += x1; x1 = rotl32(x1, 17); x1 ^= x0;
  x0 += x1; x1 = rotl32(x1, 29); x1 ^= x0;
  x0 += x1; x1 = rotl32(x1, 16); x1 ^= x0;
  x0 += x1; x1 = rotl32(x1, 24); x1 ^= x0;
  x0 += ks2; x1 += k0 + 2u;
  x0 += x1; x1 = rotl32(x1, 13); x1 ^= x0;
  x0 += x1; x1 = rotl32(x1, 15); x1 ^= x0;
  x0 += x1; x1 = rotl32(x1, 26); x1 ^= x0;
  x0 += x1; x1 = rotl32(x1, 6);  x1 ^= x0;
  x0 += k0; x1 += k1 + 3u;
  x0 += x1; x1 = rotl32(x1, 17); x1 ^= x0;
  x0 += x1; x1 = rotl32(x1, 29); x1 ^= x0;
  x0 += x1; x1 = rotl32(x1, 16); x1 ^= x0;
  x0 += x1; x1 = rotl32(x1, 24); x1 ^= x0;
  x0 += k1; x1 += ks2 + 4u;
  x0 += x1; x1 = rotl32(x1, 13); x1 ^= x0;
  x0 += x1; x1 = rotl32(x1, 15); x1 ^= x0;
  x0 += x1; x1 = rotl32(x1, 26); x1 ^= x0;
  x0 += x1; x1 = rotl32(x1, 6);  x1 ^= x0;
  o0 = x0 + ks2;
  o1 = x1 + k0 + 5u;
}

// Partitionable random_bits (32-bit): xor-fold, counter = (0, idx).
__device__ __forceinline__ uint32_t tf_fold(uint32_t k0, uint32_t k1,
                                            uint32_t idx) {
  uint32_t o0, o1;
  tf2x32(k0, k1, 0u, idx, o0, o1);
  return o0 ^ o1;
}

// Custom f64 log for x near 1 (arg is 1-xx, xx in [0, 4e-4) typical... full
// (0,2) domain handled): frexp reduction + atanh series. rel err < ~1e-15 ->
// f32 rounding identical to correctly-rounded logf w.p. ~1 - 1.7e-8 per call.
// Empirically bit-exact vs round-3 ocml-log version (absmax identical).
__device__ __forceinline__ double fast_log_f64(double x) {
  long long ix = __double_as_longlong(x);
  int e = (int)(ix >> 52) - 1023;
  double m = __longlong_as_double((ix & 0x000FFFFFFFFFFFFFLL) |
                                  0x3FF0000000000000LL);   // [1,2)
  if (m > 1.4142135623730951) { m *= 0.5; e += 1; }        // [0.7071,1.4142)
  double t  = (m - 1.0) / (m + 1.0);                       // |t| <= 0.1716
  double t2 = t * t;
  double p = 1.0 / 17.0;
  p = fma(p, t2, 1.0 / 15.0);
  p = fma(p, t2, 1.0 / 13.0);
  p = fma(p, t2, 1.0 / 11.0);
  p = fma(p, t2, 1.0 / 9.0);
  p = fma(p, t2, 1.0 / 7.0);
  p = fma(p, t2, 0.2);
  p = fma(p, t2, 1.0 / 3.0);
  p = fma(p, t2, 1.0);               // atanh(t)/t
  double lm = 2.0 * t * p;           // log(m)
  return fma((double)e, 0.6931471805599453, lm);
}

__device__ __forceinline__ float logf_cr(float t) {
  return (float)fast_log_f64((double)t);
}

// XLA log1p f32: |x|<1e-4 -> ((-0.5x)+1)*x, else log(x+1). Strict f32.
__device__ __forceinline__ float log1p_f32_xla(float x) {
  if (fabsf(x) < 1e-4f) {
    return __fmul_rn(__fadd_rn(__fmul_rn(-0.5f, x), 1.0f), x);
  }
  return logf_cr(__fadd_rn(x, 1.0f));
}

// XLA chlo erf_inv f32 expansion: strict f32 mul/add (no fma contraction).
__device__ __forceinline__ float erfinv_f32_xla(float x) {
  float xx = __fmul_rn(x, x);
  float w = -log1p_f32_xla(-xx);
  float p;
  if (w < 5.0f) {
    float ww = __fsub_rn(w, 2.5f);
    p = 2.81022636e-08f;
    p = __fadd_rn(__fmul_rn(p, ww), 3.43273939e-07f);
    p = __fadd_rn(__fmul_rn(p, ww), -3.5233877e-06f);
    p = __fadd_rn(__fmul_rn(p, ww), -4.39150654e-06f);
    p = __fadd_rn(__fmul_rn(p, ww), 0.00021858087f);
    p = __fadd_rn(__fmul_rn(p, ww), -0.00125372503f);
    p = __fadd_rn(__fmul_rn(p, ww), -0.00417768164f);
    p = __fadd_rn(__fmul_rn(p, ww), 0.246640727f);
    p = __fadd_rn(__fmul_rn(p, ww), 1.50140941f);
  } else {
    float ww = __fsub_rn(__fsqrt_rn(w), 3.0f);
    p = -0.000200214257f;
    p = __fadd_rn(__fmul_rn(p, ww), 0.000100950558f);
    p = __fadd_rn(__fmul_rn(p, ww), 0.00134934322f);
    p = __fadd_rn(__fmul_rn(p, ww), -0.00367342844f);
    p = __fadd_rn(__fmul_rn(p, ww), 0.00573950773f);
    p = __fadd_rn(__fmul_rn(p, ww), -0.0076224613f);
    p = __fadd_rn(__fmul_rn(p, ww), 0.00943887047f);
    p = __fadd_rn(__fmul_rn(p, ww), 1.00167406f);
    p = __fadd_rn(__fmul_rn(p, ww), 2.83297682f);
  }
  return __fmul_rn(p, x);
}

// jax normal f32-exact bit pipeline; noise = 0.01f*(sqrt2_f32*erfinv(u)).
__device__ __forceinline__ float noise_from_bits(uint32_t bits) {
  const float lo = __uint_as_float(0xBF7FFFFFu);        // -(1 - 2^-24)
  float f = __uint_as_float((bits >> 9) | 0x3f800000u); // [1,2)
  f = __fsub_rn(f, 1.0f);                               // [0,1), exact
  float u = __fadd_rn(__fmul_rn(f, 2.0f), lo);
  u = fmaxf(u, lo);
  float y = erfinv_f32_xla(u);
  float n = __fmul_rn(__uint_as_float(0x3FB504F3u), y); // sqrt(2) f32
  return __fmul_rn(0.01f, n);
}

// ------------- Kernel A: embedding gather + masked mean ---------------------
// Thread = (row b, quad q of 4 embed dims). Per-(b,e) sequential l order
// preserved (bit-identical; pad row is all +0.0 so unconditional add is a
// no-op). int4 token loads, float4 gathers, 4 independent add chains.
// Empirically bit-exact vs round-3 scalar version on launch 1.
__global__ __launch_bounds__(256) void embed_mean_kernel(
    const int4* __restrict__ tok4,      // tokens viewed as int4 (B*50)
    const float4* __restrict__ table4,  // table viewed as float4 (VOCAB*4)
    float4* __restrict__ avg4) {        // avg_emb viewed as float4 (B*4)
  int gt = blockIdx.x * 256 + threadIdx.x;  // 0..65535 = b*4 + q
  int b = gt >> 2, q = gt & 3;
  const int4* trow = tok4 + (size_t)b * 50;
  float a0 = 0.0f, a1 = 0.0f, a2 = 0.0f, a3 = 0.0f;
  int cnt = 0;
  for (int li = 0; li < 50; ++li) {
    int4 tk = trow[li];
    int toks[4] = {tk.x, tk.y, tk.z, tk.w};
    #pragma unroll
    for (int u = 0; u < 4; ++u) {
      int tok = toks[u];
      float4 tv = table4[(size_t)tok * 4 + q];
      a0 = __fadd_rn(a0, tv.x);
      a1 = __fadd_rn(a1, tv.y);
      a2 = __fadd_rn(a2, tv.z);
      a3 = __fadd_rn(a3, tv.w);
      cnt += (tok != 0);
    }
  }
  float valid = fmaxf((float)cnt, 1.0f);   // clip(mask.sum, 1.0)
  float4 r;
  r.x = __fdiv_rn(a0, valid);
  r.y = __fdiv_rn(a1, valid);
  r.z = __fdiv_rn(a2, valid);
  r.w = __fdiv_rn(a3, valid);
  avg4[gt] = r;
}

// ---- Kernel B: cortex recurrence — EXACT round-3 structure (LDS keys,
//      unconditional fail hash, no unroll pragma), fast_log swapped in -------
__global__ __launch_bounds__(256) void cortex_kernel(
    const float* __restrict__ avg_emb,
    const float* __restrict__ Wc, const float* __restrict__ bc,
    const float* __restrict__ Wr, const float* __restrict__ br,
    float* __restrict__ out) {
  // keys = split(key(1), 10) [foldlike]: keys[t] = tf((0,1), (0,t)) full pair.
  // kn,kf = split(keys[t], 2): kn = tf(keys[t],(0,0)), kf = tf(keys[t],(0,1)).
  __shared__ uint32_t s_kn0[TICKS], s_kn1[TICKS], s_kf0[TICKS], s_kf1[TICKS];
  if (threadIdx.x == 0) {
    for (int t = 0; t < TICKS; ++t) {
      uint32_t kt0, kt1;
      tf2x32(0u, 1u, 0u, (uint32_t)t, kt0, kt1);
      uint32_t a0, a1;
      tf2x32(kt0, kt1, 0u, 0u, a0, a1);
      s_kn0[t] = a0; s_kn1[t] = a1;
      tf2x32(kt0, kt1, 0u, 1u, a0, a1);
      s_kf0[t] = a0; s_kf1[t] = a1;
    }
  }
  __syncthreads();

  int j = blockIdx.x * 256 + threadIdx.x;   // 0..NELEM-1, = b*64 + h
  int h = j & 63;
  int b = j >> 6;

  // cur = avg_emb @ Wc^T + bc — FMA dot k ascending, then bias add.
  float wrow[EMBED];
  #pragma unroll
  for (int e = 0; e < EMBED; ++e) wrow[e] = Wc[h * EMBED + e];
  const float* ap = avg_emb + b * EMBED;
  float d = 0.0f;
  #pragma unroll
  for (int e = 0; e < EMBED; ++e) d = fmaf(ap[e], wrow[e], d);
  float cur = __fadd_rn(d, bc[h]);

  float v = 0.0f, rfr = 0.0f;
  int ac = 0;
  for (int t = 0; t < TICKS; ++t) {
    uint32_t nb = tf_fold(s_kn0[t], s_kn1[t], (uint32_t)j);
    uint32_t fb = tf_fold(s_kf0[t], s_kf1[t], (uint32_t)j);
    float z = noise_from_bits(nb);
    // v = ((v * 0.98f) + cur) + noise — strict f32
    v = __fadd_rn(__fadd_rn(__fmul_rn(v, 0.98f), cur), z);
    // fire = (v - refrac) > 0.5 && uniform >= 0.5 (MSB of fail bits)
    bool fire = (__fsub_rn(v, rfr) > 0.5f) && (fb >> 31);
    if (fire) v = 0.0f;
    rfr = __fadd_rn(__fmul_rn(rfr, 0.95f), fire ? 1.0f : 0.0f);
    ac += fire;
  }

  float s = __fdiv_rn((float)ac, 10.0f);

  // avg_spikes output (offset B*4), coalesced
  out[B_ROWS * 4 + j] = s;

  // logits = avg_spikes @ Wr^T + br — f64 butterfly over the wave's 64 h's.
  double pc[4];
  #pragma unroll
  for (int cc = 0; cc < 4; ++cc)
    pc[cc] = (double)s * (double)Wr[cc * HIDDEN + h];
  #pragma unroll
  for (int off = 32; off >= 1; off >>= 1) {
    #pragma unroll
    for (int cc = 0; cc < 4; ++cc) pc[cc] += __shfl_xor(pc[cc], off, 64);
  }
  if ((threadIdx.x & 63) == 0) {
    #pragma unroll
    for (int cc = 0; cc < 4; ++cc)
      out[b * 4 + cc] = (float)(pc[cc] + (double)br[cc]);
  }
}

extern "C" void kernel_launch(void* const* d_in, const int* in_sizes, int n_in,
                              void* d_out, int out_size, void* d_ws, size_t ws_size,
                              hipStream_t stream) {
  const int*   tokens = (const int*)d_in[0];
  const float* table  = (const float*)d_in[1];
  const float* Wc     = (const float*)d_in[2];
  const float* bc     = (const float*)d_in[3];
  const float* Wr     = (const float*)d_in[4];
  const float* br     = (const float*)d_in[5];
  float* out = (float*)d_out;
  float* avg = (float*)d_ws;   // B*EMBED f32 = 1 MB scratch

  embed_mean_kernel<<<65536 / 256, 256, 0, stream>>>(
      (const int4*)tokens, (const float4*)table, (float4*)avg);
  cortex_kernel<<<NELEM / 256, 256, 0, stream>>>(avg, Wc, bc, Wr, br, out);
}

// Round 6
// 146.097 us; speedup vs baseline: 1.3837x; 1.1510x over previous
//
#include <hip/hip_runtime.h>
#include <cstdint>
#include <math.h>

// Problem constants
#define B_ROWS 16384
#define SEQ_L  200
#define EMBED  16
#define HIDDEN 64
#define TICKS  10
#define NELEM  1048576   // B*H

// ---------------- threefry2x32 (jax partitionable), bit-exact ---------------
__host__ __device__ __forceinline__ uint32_t rotl32(uint32_t v, int r) {
  return (v << r) | (v >> (32 - r));
}

__host__ __device__ __forceinline__ void tf2x32(uint32_t k0, uint32_t k1,
                                                uint32_t x0, uint32_t x1,
                                                uint32_t& o0, uint32_t& o1) {
  uint32_t ks2 = k0 ^ k1 ^ 0x1BD11BDAu;
  x0 += k0; x1 += k1;
  x0 += x1; x1 = rotl32(x1, 13); x1 ^= x0;
  x0 += x1; x1 = rotl32(x1, 15); x1 ^= x0;
  x0 += x1; x1 = rotl32(x1, 26); x1 ^= x0;
  x0 += x1; x1 = rotl32(x1, 6);  x1 ^= x0;
  x0 += k1; x1 += ks2 + 1u;
  x0 += x1; x1 = rotl32(x1, 17); x1 ^= x0;
  x0 += x1; x1 = rotl32(x1, 29); x1 ^= x0;
  x0 += x1; x1 = rotl32(x1, 16); x1 ^= x0;
  x0 += x1; x1 = rotl32(x1, 24); x1 ^= x0;
  x0 += ks2; x1 += k0 + 2u;
  x0 += x1; x1 = rotl32(x1, 13); x1 ^= x0;
  x0 += x1; x1 = rotl32(x1, 15); x1 ^= x0;
  x0 += x1; x1 = rotl32(x1, 26); x1 ^= x0;
  x0 += x1; x1 = rotl32(x1, 6);  x1 ^= x0;
  x0 += k0; x1 += k1 + 3u;
  x0 += x1; x1 = rotl32(x1, 17); x1 ^= x0;
  x0 += x1; x1 = rotl32(x1, 29); x1 ^= x0;
  x0 += x1; x1 = rotl32(x1, 16); x1 ^= x0;
  x0 += x1; x1 = rotl32(x1, 24); x1 ^= x0;
  x0 += k1; x1 += ks2 + 4u;
  x0 += x1; x1 = rotl32(x1, 13); x1 ^= x0;
  x0 += x1; x1 = rotl32(x1, 15); x1 ^= x0;
  x0 += x1; x1 = rotl32(x1, 26); x1 ^= x0;
  x0 += x1; x1 = rotl32(x1, 6);  x1 ^= x0;
  o0 = x0 + ks2;
  o1 = x1 + k0 + 5u;
}

// Per-tick kn/kf key pairs, computed on the HOST each launch and passed as a
// by-value kernel argument (lands in kernarg/SGPRs; no LDS, no syncthreads).
struct Keys { uint32_t n0[TICKS], n1[TICKS], f0[TICKS], f1[TICKS]; };

// Partitionable random_bits (32-bit): xor-fold, counter = (0, idx).
__device__ __forceinline__ uint32_t tf_fold(uint32_t k0, uint32_t k1,
                                            uint32_t idx) {
  uint32_t o0, o1;
  tf2x32(k0, k1, 0u, idx, o0, o1);
  return o0 ^ o1;
}

// Custom f64 log: frexp reduction + atanh series. rel err < ~1e-15 ->
// f32 rounding identical to correctly-rounded logf w.p. ~1 - 1.7e-8 per call.
// Empirically bit-exact vs ocml log on this workload (rounds 3/5 absmax equal).
__device__ __forceinline__ double fast_log_f64(double x) {
  long long ix = __double_as_longlong(x);
  int e = (int)(ix >> 52) - 1023;
  double m = __longlong_as_double((ix & 0x000FFFFFFFFFFFFFLL) |
                                  0x3FF0000000000000LL);   // [1,2)
  if (m > 1.4142135623730951) { m *= 0.5; e += 1; }        // [0.7071,1.4142)
  double t  = (m - 1.0) / (m + 1.0);                       // |t| <= 0.1716
  double t2 = t * t;
  double p = 1.0 / 17.0;
  p = fma(p, t2, 1.0 / 15.0);
  p = fma(p, t2, 1.0 / 13.0);
  p = fma(p, t2, 1.0 / 11.0);
  p = fma(p, t2, 1.0 / 9.0);
  p = fma(p, t2, 1.0 / 7.0);
  p = fma(p, t2, 0.2);
  p = fma(p, t2, 1.0 / 3.0);
  p = fma(p, t2, 1.0);               // atanh(t)/t
  double lm = 2.0 * t * p;           // log(m)
  return fma((double)e, 0.6931471805599453, lm);
}

__device__ __forceinline__ float logf_cr(float t) {
  return (float)fast_log_f64((double)t);
}

// XLA log1p f32: |x|<1e-4 -> ((-0.5x)+1)*x, else log(x+1). Strict f32.
__device__ __forceinline__ float log1p_f32_xla(float x) {
  if (fabsf(x) < 1e-4f) {
    return __fmul_rn(__fadd_rn(__fmul_rn(-0.5f, x), 1.0f), x);
  }
  return logf_cr(__fadd_rn(x, 1.0f));
}

// XLA chlo erf_inv f32 expansion: strict f32 mul/add (no fma contraction).
__device__ __forceinline__ float erfinv_f32_xla(float x) {
  float xx = __fmul_rn(x, x);
  float w = -log1p_f32_xla(-xx);
  float p;
  if (w < 5.0f) {
    float ww = __fsub_rn(w, 2.5f);
    p = 2.81022636e-08f;
    p = __fadd_rn(__fmul_rn(p, ww), 3.43273939e-07f);
    p = __fadd_rn(__fmul_rn(p, ww), -3.5233877e-06f);
    p = __fadd_rn(__fmul_rn(p, ww), -4.39150654e-06f);
    p = __fadd_rn(__fmul_rn(p, ww), 0.00021858087f);
    p = __fadd_rn(__fmul_rn(p, ww), -0.00125372503f);
    p = __fadd_rn(__fmul_rn(p, ww), -0.00417768164f);
    p = __fadd_rn(__fmul_rn(p, ww), 0.246640727f);
    p = __fadd_rn(__fmul_rn(p, ww), 1.50140941f);
  } else {
    float ww = __fsub_rn(__fsqrt_rn(w), 3.0f);
    p = -0.000200214257f;
    p = __fadd_rn(__fmul_rn(p, ww), 0.000100950558f);
    p = __fadd_rn(__fmul_rn(p, ww), 0.00134934322f);
    p = __fadd_rn(__fmul_rn(p, ww), -0.00367342844f);
    p = __fadd_rn(__fmul_rn(p, ww), 0.00573950773f);
    p = __fadd_rn(__fmul_rn(p, ww), -0.0076224613f);
    p = __fadd_rn(__fmul_rn(p, ww), 0.00943887047f);
    p = __fadd_rn(__fmul_rn(p, ww), 1.00167406f);
    p = __fadd_rn(__fmul_rn(p, ww), 2.83297682f);
  }
  return __fmul_rn(p, x);
}

// jax normal f32-exact bit pipeline; noise = 0.01f*(sqrt2_f32*erfinv(u)).
__device__ __forceinline__ float noise_from_bits(uint32_t bits) {
  const float lo = __uint_as_float(0xBF7FFFFFu);        // -(1 - 2^-24)
  float f = __uint_as_float((bits >> 9) | 0x3f800000u); // [1,2)
  f = __fsub_rn(f, 1.0f);                               // [0,1), exact
  float u = __fadd_rn(__fmul_rn(f, 2.0f), lo);
  u = fmaxf(u, lo);
  float y = erfinv_f32_xla(u);
  float n = __fmul_rn(__uint_as_float(0x3FB504F3u), y); // sqrt(2) f32
  return __fmul_rn(0.01f, n);
}

// ------------- Kernel A: embedding gather + masked mean ---------------------
// Thread = (row b, embed dim e); 16 rows per 256-thread block -> 1024 blocks
// (4 waves/SIMD). Tokens staged in LDS via coalesced int4 (each token line
// read once from HBM). Table gathers software-pipelined 8-deep, double
// buffered: next 8 issued before current 8 are consumed -> adds wait at
// vmcnt(8), 16 outstanding loads/wave. Per-(b,e) f32 add order l=0..199
// strictly preserved (bit-identical to rounds 3/5).
__global__ __launch_bounds__(256) void embed_mean_kernel(
    const int4* __restrict__ tok4,       // tokens as int4 (B*50)
    const float* __restrict__ table,     // VOCAB x 16
    float* __restrict__ avg_emb) {       // B x 16
  __shared__ int s_tok[16 * SEQ_L];
  int tid = threadIdx.x;
  {
    const int4* g4 = tok4 + (size_t)blockIdx.x * (16 * 50);
    int4* s4 = (int4*)s_tok;
    #pragma unroll
    for (int i = 0; i < 4; ++i) s4[tid + 256 * i] = g4[tid + 256 * i];
  }
  __syncthreads();

  int r = tid >> 4, e = tid & 15;
  int b = blockIdx.x * 16 + r;
  const int* trow = s_tok + r * SEQ_L;

  float acc = 0.0f;
  int cnt = 0;
  float buf0[8], buf1[8];

  #pragma unroll
  for (int p = 0; p < 8; ++p) {             // prologue: l = 0..7
    int tk = trow[p];
    cnt += (tk != 0);
    buf0[p] = table[(size_t)tk * EMBED + e];
  }
  // 200 = 8 + 12*16: 12 double-group iterations
  for (int l0 = 0; l0 < 192; l0 += 16) {
    #pragma unroll
    for (int p = 0; p < 8; ++p) {           // issue l0+8 .. l0+15
      int tk = trow[l0 + 8 + p];
      cnt += (tk != 0);
      buf1[p] = table[(size_t)tk * EMBED + e];
    }
    #pragma unroll
    for (int p = 0; p < 8; ++p) acc = __fadd_rn(acc, buf0[p]);  // l0..l0+7
    #pragma unroll
    for (int p = 0; p < 8; ++p) {           // issue l0+16 .. l0+23 (max 199)
      int tk = trow[l0 + 16 + p];
      cnt += (tk != 0);
      buf0[p] = table[(size_t)tk * EMBED + e];
    }
    #pragma unroll
    for (int p = 0; p < 8; ++p) acc = __fadd_rn(acc, buf1[p]);  // l0+8..l0+15
  }
  #pragma unroll
  for (int p = 0; p < 8; ++p) acc = __fadd_rn(acc, buf0[p]);    // l = 192..199

  float valid = fmaxf((float)cnt, 1.0f);    // clip(mask.sum, 1.0)
  avg_emb[b * EMBED + e] = __fdiv_rn(acc, valid);
}

// ---- Kernel B: cortex recurrence — numerics identical to round 5; keys via
//      kernarg (SGPRs), tick loop fully unrolled. --------------------------
__global__ __launch_bounds__(256) void cortex_kernel(
    const float* __restrict__ avg_emb,
    const float* __restrict__ Wc, const float* __restrict__ bc,
    const float* __restrict__ Wr, const float* __restrict__ br,
    float* __restrict__ out, Keys K) {
  int j = blockIdx.x * 256 + threadIdx.x;   // 0..NELEM-1, = b*64 + h
  int h = j & 63;
  int b = j >> 6;

  // cur = avg_emb @ Wc^T + bc — FMA dot k ascending, then bias add.
  float wrow[EMBED];
  #pragma unroll
  for (int e = 0; e < EMBED; ++e) wrow[e] = Wc[h * EMBED + e];
  const float* ap = avg_emb + b * EMBED;
  float d = 0.0f;
  #pragma unroll
  for (int e = 0; e < EMBED; ++e) d = fmaf(ap[e], wrow[e], d);
  float cur = __fadd_rn(d, bc[h]);

  float v = 0.0f, rfr = 0.0f;
  int ac = 0;
  #pragma unroll
  for (int t = 0; t < TICKS; ++t) {
    uint32_t nb = tf_fold(K.n0[t], K.n1[t], (uint32_t)j);
    uint32_t fb = tf_fold(K.f0[t], K.f1[t], (uint32_t)j);
    float z = noise_from_bits(nb);
    // v = ((v * 0.98f) + cur) + noise — strict f32
    v = __fadd_rn(__fadd_rn(__fmul_rn(v, 0.98f), cur), z);
    // fire = (v - refrac) > 0.5 && uniform >= 0.5 (MSB of fail bits)
    bool fire = (__fsub_rn(v, rfr) > 0.5f) && (fb >> 31);
    if (fire) v = 0.0f;
    rfr = __fadd_rn(__fmul_rn(rfr, 0.95f), fire ? 1.0f : 0.0f);
    ac += fire;
  }

  float s = __fdiv_rn((float)ac, 10.0f);

  // avg_spikes output (offset B*4), coalesced
  out[B_ROWS * 4 + j] = s;

  // logits = avg_spikes @ Wr^T + br — f64 butterfly over the wave's 64 h's.
  double pc[4];
  #pragma unroll
  for (int cc = 0; cc < 4; ++cc)
    pc[cc] = (double)s * (double)Wr[cc * HIDDEN + h];
  #pragma unroll
  for (int off = 32; off >= 1; off >>= 1) {
    #pragma unroll
    for (int cc = 0; cc < 4; ++cc) pc[cc] += __shfl_xor(pc[cc], off, 64);
  }
  if ((threadIdx.x & 63) == 0) {
    #pragma unroll
    for (int cc = 0; cc < 4; ++cc)
      out[b * 4 + cc] = (float)(pc[cc] + (double)br[cc]);
  }
}

extern "C" void kernel_launch(void* const* d_in, const int* in_sizes, int n_in,
                              void* d_out, int out_size, void* d_ws, size_t ws_size,
                              hipStream_t stream) {
  const int*   tokens = (const int*)d_in[0];
  const float* table  = (const float*)d_in[1];
  const float* Wc     = (const float*)d_in[2];
  const float* bc     = (const float*)d_in[3];
  const float* Wr     = (const float*)d_in[4];
  const float* br     = (const float*)d_in[5];
  float* out = (float*)d_out;
  float* avg = (float*)d_ws;   // B*EMBED f32 = 1 MB scratch

  // Host-side threefry key derivation (identical every call — deterministic):
  // keys[t] = tf((0,1),(0,t)); kn = tf(keys[t],(0,0)); kf = tf(keys[t],(0,1)).
  Keys K;
  for (int t = 0; t < TICKS; ++t) {
    uint32_t kt0, kt1, a0, a1;
    tf2x32(0u, 1u, 0u, (uint32_t)t, kt0, kt1);
    tf2x32(kt0, kt1, 0u, 0u, a0, a1);
    K.n0[t] = a0; K.n1[t] = a1;
    tf2x32(kt0, kt1, 0u, 1u, a0, a1);
    K.f0[t] = a0; K.f1[t] = a1;
  }

  embed_mean_kernel<<<B_ROWS / 16, 256, 0, stream>>>(
      (const int4*)tokens, table, avg);
  cortex_kernel<<<NELEM / 256, 256, 0, stream>>>(avg, Wc, bc, Wr, br, out, K);
}

// Round 7
// 137.637 us; speedup vs baseline: 1.4688x; 1.0615x over previous
//
#include <hip/hip_runtime.h>
#include <cstdint>
#include <math.h>

// Problem constants
#define B_ROWS 16384
#define SEQ_L  200
#define EMBED  16
#define HIDDEN 64
#define TICKS  10
#define NELEM  1048576   // B*H

// ---------------- threefry2x32 (jax partitionable), bit-exact ---------------
__host__ __device__ __forceinline__ uint32_t rotl32(uint32_t v, int r) {
  return (v << r) | (v >> (32 - r));
}

__host__ __device__ __forceinline__ void tf2x32(uint32_t k0, uint32_t k1,
                                                uint32_t x0, uint32_t x1,
                                                uint32_t& o0, uint32_t& o1) {
  uint32_t ks2 = k0 ^ k1 ^ 0x1BD11BDAu;
  x0 += k0; x1 += k1;
  x0 += x1; x1 = rotl32(x1, 13); x1 ^= x0;
  x0 += x1; x1 = rotl32(x1, 15); x1 ^= x0;
  x0 += x1; x1 = rotl32(x1, 26); x1 ^= x0;
  x0 += x1; x1 = rotl32(x1, 6);  x1 ^= x0;
  x0 += k1; x1 += ks2 + 1u;
  x0 += x1; x1 = rotl32(x1, 17); x1 ^= x0;
  x0 += x1; x1 = rotl32(x1, 29); x1 ^= x0;
  x0 += x1; x1 = rotl32(x1, 16); x1 ^= x0;
  x0 += x1; x1 = rotl32(x1, 24); x1 ^= x0;
  x0 += ks2; x1 += k0 + 2u;
  x0 += x1; x1 = rotl32(x1, 13); x1 ^= x0;
  x0 += x1; x1 = rotl32(x1, 15); x1 ^= x0;
  x0 += x1; x1 = rotl32(x1, 26); x1 ^= x0;
  x0 += x1; x1 = rotl32(x1, 6);  x1 ^= x0;
  x0 += k0; x1 += k1 + 3u;
  x0 += x1; x1 = rotl32(x1, 17); x1 ^= x0;
  x0 += x1; x1 = rotl32(x1, 29); x1 ^= x0;
  x0 += x1; x1 = rotl32(x1, 16); x1 ^= x0;
  x0 += x1; x1 = rotl32(x1, 24); x1 ^= x0;
  x0 += k1; x1 += ks2 + 4u;
  x0 += x1; x1 = rotl32(x1, 13); x1 ^= x0;
  x0 += x1; x1 = rotl32(x1, 15); x1 ^= x0;
  x0 += x1; x1 = rotl32(x1, 26); x1 ^= x0;
  x0 += x1; x1 = rotl32(x1, 6);  x1 ^= x0;
  o0 = x0 + ks2;
  o1 = x1 + k0 + 5u;
}

// Per-tick kn/kf key pairs, host-derived, passed by value (kernarg/SGPRs).
struct Keys { uint32_t n0[TICKS], n1[TICKS], f0[TICKS], f1[TICKS]; };

// Partitionable random_bits (32-bit): xor-fold, counter = (0, idx).
__device__ __forceinline__ uint32_t tf_fold(uint32_t k0, uint32_t k1,
                                            uint32_t idx) {
  uint32_t o0, o1;
  tf2x32(k0, k1, 0u, idx, o0, o1);
  return o0 ^ o1;
}

// Custom f64 log: frexp reduction + atanh series. rel err < ~1e-15 ->
// f32 rounding identical to correctly-rounded logf w.p. ~1 - 1.7e-8 per call.
// Proven bit-compatible on this workload (rounds 3..6 absmax identical).
__device__ __forceinline__ double fast_log_f64(double x) {
  long long ix = __double_as_longlong(x);
  int e = (int)(ix >> 52) - 1023;
  double m = __longlong_as_double((ix & 0x000FFFFFFFFFFFFFLL) |
                                  0x3FF0000000000000LL);   // [1,2)
  if (m > 1.4142135623730951) { m *= 0.5; e += 1; }        // [0.7071,1.4142)
  double t  = (m - 1.0) / (m + 1.0);                       // |t| <= 0.1716
  double t2 = t * t;
  double p = 1.0 / 17.0;
  p = fma(p, t2, 1.0 / 15.0);
  p = fma(p, t2, 1.0 / 13.0);
  p = fma(p, t2, 1.0 / 11.0);
  p = fma(p, t2, 1.0 / 9.0);
  p = fma(p, t2, 1.0 / 7.0);
  p = fma(p, t2, 0.2);
  p = fma(p, t2, 1.0 / 3.0);
  p = fma(p, t2, 1.0);               // atanh(t)/t
  double lm = 2.0 * t * p;           // log(m)
  return fma((double)e, 0.6931471805599453, lm);
}

__device__ __forceinline__ float logf_cr(float t) {
  return (float)fast_log_f64((double)t);
}

// XLA log1p f32: |x|<1e-4 -> ((-0.5x)+1)*x, else log(x+1). Strict f32.
__device__ __forceinline__ float log1p_f32_xla(float x) {
  if (fabsf(x) < 1e-4f) {
    return __fmul_rn(__fadd_rn(__fmul_rn(-0.5f, x), 1.0f), x);
  }
  return logf_cr(__fadd_rn(x, 1.0f));
}

// XLA chlo erf_inv f32 expansion: strict f32 mul/add (no fma contraction).
__device__ __forceinline__ float erfinv_f32_xla(float x) {
  float xx = __fmul_rn(x, x);
  float w = -log1p_f32_xla(-xx);
  float p;
  if (w < 5.0f) {
    float ww = __fsub_rn(w, 2.5f);
    p = 2.81022636e-08f;
    p = __fadd_rn(__fmul_rn(p, ww), 3.43273939e-07f);
    p = __fadd_rn(__fmul_rn(p, ww), -3.5233877e-06f);
    p = __fadd_rn(__fmul_rn(p, ww), -4.39150654e-06f);
    p = __fadd_rn(__fmul_rn(p, ww), 0.00021858087f);
    p = __fadd_rn(__fmul_rn(p, ww), -0.00125372503f);
    p = __fadd_rn(__fmul_rn(p, ww), -0.00417768164f);
    p = __fadd_rn(__fmul_rn(p, ww), 0.246640727f);
    p = __fadd_rn(__fmul_rn(p, ww), 1.50140941f);
  } else {
    float ww = __fsub_rn(__fsqrt_rn(w), 3.0f);
    p = -0.000200214257f;
    p = __fadd_rn(__fmul_rn(p, ww), 0.000100950558f);
    p = __fadd_rn(__fmul_rn(p, ww), 0.00134934322f);
    p = __fadd_rn(__fmul_rn(p, ww), -0.00367342844f);
    p = __fadd_rn(__fmul_rn(p, ww), 0.00573950773f);
    p = __fadd_rn(__fmul_rn(p, ww), -0.0076224613f);
    p = __fadd_rn(__fmul_rn(p, ww), 0.00943887047f);
    p = __fadd_rn(__fmul_rn(p, ww), 1.00167406f);
    p = __fadd_rn(__fmul_rn(p, ww), 2.83297682f);
  }
  return __fmul_rn(p, x);
}

// jax normal f32-exact bit pipeline; noise = 0.01f*(sqrt2_f32*erfinv(u)).
__device__ __forceinline__ float noise_from_bits(uint32_t bits) {
  const float lo = __uint_as_float(0xBF7FFFFFu);        // -(1 - 2^-24)
  float f = __uint_as_float((bits >> 9) | 0x3f800000u); // [1,2)
  f = __fsub_rn(f, 1.0f);                               // [0,1), exact
  float u = __fadd_rn(__fmul_rn(f, 2.0f), lo);
  u = fmaxf(u, lo);
  float y = erfinv_f32_xla(u);
  float n = __fmul_rn(__uint_as_float(0x3FB504F3u), y); // sqrt(2) f32
  return __fmul_rn(0.01f, n);
}

// --------------- Fused kernel: one wave == one row b -----------------------
// Embed phase: lanes = (q = token phase i&3, e = embed dim). 4 phases gather
// in parallel (4x shorter dependent chain, depth-10 double-buffered); the
// 200 adds run in exact i=0..199 order via __shfl from lane m*16+e ->
// bit-identical to the round-3/5/6 sequential f32 chain. avg stays in-wave.
// Cortex phase: byte-for-byte round-6 numerics + execz fail-hash skip.
__global__ __launch_bounds__(256) void fused_kernel(
    const int* __restrict__ tokens, const float* __restrict__ table,
    const float* __restrict__ Wc, const float* __restrict__ bc,
    const float* __restrict__ Wr, const float* __restrict__ br,
    float* __restrict__ out, Keys K) {
  int tid  = threadIdx.x;
  int wv   = tid >> 6, lane = tid & 63;
  int b    = blockIdx.x * 4 + wv;          // this wave's row
  int e    = lane & 15, q = lane >> 4;     // embed dim, token phase
  int j    = b * HIDDEN + lane;            // cortex element (h = lane)

  const int* gtok = tokens + (size_t)b * SEQ_L;

  // ---- embed: 5 groups of 10 steps; step k covers tokens i = 4k..4k+3 ----
  float g0[10], g1[10];
  int tA[10], tB[10];
  int c0 = 0;        // per-lane nonzero count (its 50 q-phase tokens)
  float acc = 0.0f;  // full 200-add chain, every lane (redundant x4)

  #define LD_T(buf, base)                                            \
    _Pragma("unroll") for (int p = 0; p < 10; ++p)                   \
        buf[p] = gtok[4 * ((base) + p) + q];
  #define GA_T(gbuf, buf)                                            \
    _Pragma("unroll") for (int p = 0; p < 10; ++p) {                 \
      c0 += (buf[p] != 0);                                           \
      gbuf[p] = table[(size_t)buf[p] * EMBED + e];                   \
    }
  #define CONSUME(gbuf)                                              \
    _Pragma("unroll") for (int p = 0; p < 10; ++p) {                 \
      _Pragma("unroll") for (int m = 0; m < 4; ++m)                  \
        acc = __fadd_rn(acc, __shfl(gbuf[p], m * 16 + e, 64));       \
    }

  LD_T(tA, 0);  GA_T(g0, tA);
  LD_T(tB, 10); GA_T(g1, tB); CONSUME(g0);   // i   0.. 39
  LD_T(tA, 20); GA_T(g0, tA); CONSUME(g1);   // i  40.. 79
  LD_T(tB, 30); GA_T(g1, tB); CONSUME(g0);   // i  80..119
  LD_T(tA, 40); GA_T(g0, tA); CONSUME(g1);   // i 120..159
  CONSUME(g0);                               // i 160..199
  #undef LD_T
  #undef GA_T
  #undef CONSUME

  int cnt = c0;
  cnt += __shfl_xor(cnt, 16, 64);
  cnt += __shfl_xor(cnt, 32, 64);
  float valid = fmaxf((float)cnt, 1.0f);          // clip(mask.sum, 1.0)
  float avgv = __fdiv_rn(acc, valid);             // avg_emb[b][e], bit-exact

  // ---- cur = avg_emb @ Wc^T + bc (h = lane), FMA dot e ascending ----------
  int h = lane;
  float d = 0.0f;
  #pragma unroll
  for (int e2 = 0; e2 < EMBED; ++e2) {
    float ae = __shfl(avgv, e2, 64);              // same f32 bits as r6 path
    d = fmaf(ae, Wc[h * EMBED + e2], d);
  }
  float cur = __fadd_rn(d, bc[h]);

  // ---- cortex recurrence: round-6 numerics + execz fail-skip --------------
  float v = 0.0f, rfr = 0.0f;
  int ac = 0;
  #pragma unroll
  for (int t = 0; t < TICKS; ++t) {
    uint32_t nb = tf_fold(K.n0[t], K.n1[t], (uint32_t)j);
    float z = noise_from_bits(nb);
    // v = ((v * 0.98f) + cur) + noise — strict f32
    v = __fadd_rn(__fadd_rn(__fmul_rn(v, 0.98f), cur), z);
    bool cand = (__fsub_rn(v, rfr) > 0.5f);
    bool fire = false;
    if (cand) {   // divergent skip: wave with no candidates skips the hash
      uint32_t fb = tf_fold(K.f0[t], K.f1[t], (uint32_t)j);
      fire = (fb >> 31) != 0u;   // uniform >= 0.5 == MSB set
    }
    if (fire) v = 0.0f;
    rfr = __fadd_rn(__fmul_rn(rfr, 0.95f), fire ? 1.0f : 0.0f);
    ac += fire;
  }

  float s = __fdiv_rn((float)ac, 10.0f);

  // avg_spikes output (offset B*4), coalesced
  out[B_ROWS * 4 + j] = s;

  // logits = avg_spikes @ Wr^T + br — f64 butterfly over the wave's 64 h's.
  double pc[4];
  #pragma unroll
  for (int cc = 0; cc < 4; ++cc)
    pc[cc] = (double)s * (double)Wr[cc * HIDDEN + h];
  #pragma unroll
  for (int off = 32; off >= 1; off >>= 1) {
    #pragma unroll
    for (int cc = 0; cc < 4; ++cc) pc[cc] += __shfl_xor(pc[cc], off, 64);
  }
  if (lane == 0) {
    #pragma unroll
    for (int cc = 0; cc < 4; ++cc)
      out[b * 4 + cc] = (float)(pc[cc] + (double)br[cc]);
  }
}

extern "C" void kernel_launch(void* const* d_in, const int* in_sizes, int n_in,
                              void* d_out, int out_size, void* d_ws, size_t ws_size,
                              hipStream_t stream) {
  const int*   tokens = (const int*)d_in[0];
  const float* table  = (const float*)d_in[1];
  const float* Wc     = (const float*)d_in[2];
  const float* bc     = (const float*)d_in[3];
  const float* Wr     = (const float*)d_in[4];
  const float* br     = (const float*)d_in[5];
  float* out = (float*)d_out;

  // Host-side threefry key derivation (identical every call — deterministic).
  Keys K;
  for (int t = 0; t < TICKS; ++t) {
    uint32_t kt0, kt1, a0, a1;
    tf2x32(0u, 1u, 0u, (uint32_t)t, kt0, kt1);
    tf2x32(kt0, kt1, 0u, 0u, a0, a1);
    K.n0[t] = a0; K.n1[t] = a1;
    tf2x32(kt0, kt1, 0u, 1u, a0, a1);
    K.f0[t] = a0; K.f1[t] = a1;
  }

  fused_kernel<<<B_ROWS / 4, 256, 0, stream>>>(
      tokens, table, Wc, bc, Wr, br, out, K);
}

// Round 8
// 135.577 us; speedup vs baseline: 1.4911x; 1.0152x over previous
//
#include <hip/hip_runtime.h>
#include <cstdint>
#include <math.h>

// Problem constants
#define B_ROWS 16384
#define SEQ_L  200
#define EMBED  16
#define HIDDEN 64
#define TICKS  10
#define NELEM  1048576   // B*H

// ---------------- threefry2x32 (jax partitionable), bit-exact ---------------
__host__ __device__ __forceinline__ uint32_t rotl32(uint32_t v, int r) {
  return (v << r) | (v >> (32 - r));
}

__host__ __device__ __forceinline__ void tf2x32(uint32_t k0, uint32_t k1,
                                                uint32_t x0, uint32_t x1,
                                                uint32_t& o0, uint32_t& o1) {
  uint32_t ks2 = k0 ^ k1 ^ 0x1BD11BDAu;
  x0 += k0; x1 += k1;
  x0 += x1; x1 = rotl32(x1, 13); x1 ^= x0;
  x0 += x1; x1 = rotl32(x1, 15); x1 ^= x0;
  x0 += x1; x1 = rotl32(x1, 26); x1 ^= x0;
  x0 += x1; x1 = rotl32(x1, 6);  x1 ^= x0;
  x0 += k1; x1 += ks2 + 1u;
  x0 += x1; x1 = rotl32(x1, 17); x1 ^= x0;
  x0 += x1; x1 = rotl32(x1, 29); x1 ^= x0;
  x0 += x1; x1 = rotl32(x1, 16); x1 ^= x0;
  x0 += x1; x1 = rotl32(x1, 24); x1 ^= x0;
  x0 += ks2; x1 += k0 + 2u;
  x0 += x1; x1 = rotl32(x1, 13); x1 ^= x0;
  x0 += x1; x1 = rotl32(x1, 15); x1 ^= x0;
  x0 += x1; x1 = rotl32(x1, 26); x1 ^= x0;
  x0 += x1; x1 = rotl32(x1, 6);  x1 ^= x0;
  x0 += k0; x1 += k1 + 3u;
  x0 += x1; x1 = rotl32(x1, 17); x1 ^= x0;
  x0 += x1; x1 = rotl32(x1, 29); x1 ^= x0;
  x0 += x1; x1 = rotl32(x1, 16); x1 ^= x0;
  x0 += x1; x1 = rotl32(x1, 24); x1 ^= x0;
  x0 += k1; x1 += ks2 + 4u;
  x0 += x1; x1 = rotl32(x1, 13); x1 ^= x0;
  x0 += x1; x1 = rotl32(x1, 15); x1 ^= x0;
  x0 += x1; x1 = rotl32(x1, 26); x1 ^= x0;
  x0 += x1; x1 = rotl32(x1, 6);  x1 ^= x0;
  o0 = x0 + ks2;
  o1 = x1 + k0 + 5u;
}

// Per-tick kn/kf key pairs, host-derived, passed by value (kernarg/SGPRs).
struct Keys { uint32_t n0[TICKS], n1[TICKS], f0[TICKS], f1[TICKS]; };

// Partitionable random_bits (32-bit): xor-fold, counter = (0, idx).
__device__ __forceinline__ uint32_t tf_fold(uint32_t k0, uint32_t k1,
                                            uint32_t idx) {
  uint32_t o0, o1;
  tf2x32(k0, k1, 0u, idx, o0, o1);
  return o0 ^ o1;
}

// Custom f64 log: frexp reduction + atanh series (8 terms, trunc rel err
// ~3e-14) with the f64 divide replaced by Newton refinement from a
// v_rcp_f32 seed (final rel err ~3e-16). f32 rounding of the result is
// identical to a correctly-rounded logf except w.p. ~<1e-6 per call ->
// expected 0 spike flips over 10.5M decisions.
__device__ __forceinline__ double fast_log_f64(double x) {
  long long ix = __double_as_longlong(x);
  int e = (int)(ix >> 52) - 1023;
  double m = __longlong_as_double((ix & 0x000FFFFFFFFFFFFFLL) |
                                  0x3FF0000000000000LL);   // [1,2)
  if (m > 1.4142135623730951) { m *= 0.5; e += 1; }        // [0.7071,1.4142)
  double a = m - 1.0, bden = m + 1.0;                      // bden in [1.71,2.41]
  // t = a/bden via rcp_f32 seed + Newton (no v_div_* sequence):
  double r0 = (double)__builtin_amdgcn_rcpf((float)bden);  // rel err ~1e-7
  double e0 = fma(-bden, r0, 1.0);
  double r1 = fma(r0, e0, r0);                             // rel err ~1.5e-14
  double t0 = a * r1;
  double et = fma(-t0, bden, a);                           // exact remainder
  double t  = fma(et, r1, t0);                             // rel err ~3e-16
  double t2 = t * t;                                       // |t| <= 0.1716
  double p = 1.0 / 15.0;
  p = fma(p, t2, 1.0 / 13.0);
  p = fma(p, t2, 1.0 / 11.0);
  p = fma(p, t2, 1.0 / 9.0);
  p = fma(p, t2, 1.0 / 7.0);
  p = fma(p, t2, 0.2);
  p = fma(p, t2, 1.0 / 3.0);
  p = fma(p, t2, 1.0);               // atanh(t)/t
  double lm = 2.0 * t * p;           // log(m)
  return fma((double)e, 0.6931471805599453, lm);
}

__device__ __forceinline__ float logf_cr(float t) {
  return (float)fast_log_f64((double)t);
}

// XLA log1p f32: |x|<1e-4 -> ((-0.5x)+1)*x, else log(x+1). Strict f32.
__device__ __forceinline__ float log1p_f32_xla(float x) {
  if (fabsf(x) < 1e-4f) {
    return __fmul_rn(__fadd_rn(__fmul_rn(-0.5f, x), 1.0f), x);
  }
  return logf_cr(__fadd_rn(x, 1.0f));
}

// XLA chlo erf_inv f32 expansion: strict f32 mul/add (no fma contraction).
__device__ __forceinline__ float erfinv_f32_xla(float x) {
  float xx = __fmul_rn(x, x);
  float w = -log1p_f32_xla(-xx);
  float p;
  if (w < 5.0f) {
    float ww = __fsub_rn(w, 2.5f);
    p = 2.81022636e-08f;
    p = __fadd_rn(__fmul_rn(p, ww), 3.43273939e-07f);
    p = __fadd_rn(__fmul_rn(p, ww), -3.5233877e-06f);
    p = __fadd_rn(__fmul_rn(p, ww), -4.39150654e-06f);
    p = __fadd_rn(__fmul_rn(p, ww), 0.00021858087f);
    p = __fadd_rn(__fmul_rn(p, ww), -0.00125372503f);
    p = __fadd_rn(__fmul_rn(p, ww), -0.00417768164f);
    p = __fadd_rn(__fmul_rn(p, ww), 0.246640727f);
    p = __fadd_rn(__fmul_rn(p, ww), 1.50140941f);
  } else {
    float ww = __fsub_rn(__fsqrt_rn(w), 3.0f);
    p = -0.000200214257f;
    p = __fadd_rn(__fmul_rn(p, ww), 0.000100950558f);
    p = __fadd_rn(__fmul_rn(p, ww), 0.00134934322f);
    p = __fadd_rn(__fmul_rn(p, ww), -0.00367342844f);
    p = __fadd_rn(__fmul_rn(p, ww), 0.00573950773f);
    p = __fadd_rn(__fmul_rn(p, ww), -0.0076224613f);
    p = __fadd_rn(__fmul_rn(p, ww), 0.00943887047f);
    p = __fadd_rn(__fmul_rn(p, ww), 1.00167406f);
    p = __fadd_rn(__fmul_rn(p, ww), 2.83297682f);
  }
  return __fmul_rn(p, x);
}

// jax normal f32-exact bit pipeline; noise = 0.01f*(sqrt2_f32*erfinv(u)).
__device__ __forceinline__ float noise_from_bits(uint32_t bits) {
  const float lo = __uint_as_float(0xBF7FFFFFu);        // -(1 - 2^-24)
  float f = __uint_as_float((bits >> 9) | 0x3f800000u); // [1,2)
  f = __fsub_rn(f, 1.0f);                               // [0,1), exact
  float u = __fadd_rn(__fmul_rn(f, 2.0f), lo);
  u = fmaxf(u, lo);
  float y = erfinv_f32_xla(u);
  float n = __fmul_rn(__uint_as_float(0x3FB504F3u), y); // sqrt(2) f32
  return __fmul_rn(0.01f, n);
}

// Cross-lane pull via explicit ds_bpermute (byte index precomputed once) —
// bit-identical to __shfl, but the index VGPR is hoisted out of the chain.
__device__ __forceinline__ float bperm_f32(int byte_idx, float v) {
  return __int_as_float(
      __builtin_amdgcn_ds_bpermute(byte_idx, __float_as_int(v)));
}

// --------------- Fused kernel: one wave == one row b -----------------------
// Embed phase: lanes = (q = token phase i&3, e = embed dim). 4 phases gather
// in parallel (depth-10 double-buffered); the 200 adds run in exact i=0..199
// order via ds_bpermute from lane m*16+e -> bit-identical to the sequential
// f32 chain (rounds 3..7). avg stays in-wave. Cortex: round-7 numerics.
__global__ __launch_bounds__(256) void fused_kernel(
    const int* __restrict__ tokens, const float* __restrict__ table,
    const float* __restrict__ Wc, const float* __restrict__ bc,
    const float* __restrict__ Wr, const float* __restrict__ br,
    float* __restrict__ out, Keys K) {
  int tid  = threadIdx.x;
  int wv   = tid >> 6, lane = tid & 63;
  int b    = blockIdx.x * 4 + wv;          // this wave's row
  int e    = lane & 15, q = lane >> 4;     // embed dim, token phase
  int j    = b * HIDDEN + lane;            // cortex element (h = lane)

  const int* gtok = tokens + (size_t)b * SEQ_L;

  // hoisted bpermute byte-indices for the 4 phase sources (lane m*16+e)
  int bp0 = e << 2, bp1 = (16 + e) << 2, bp2 = (32 + e) << 2,
      bp3 = (48 + e) << 2;

  // ---- embed: 5 groups of 10 steps; step k covers tokens i = 4k..4k+3 ----
  float g0[10], g1[10];
  int tA[10], tB[10];
  int c0 = 0;        // per-lane nonzero count (its 50 q-phase tokens)
  float acc = 0.0f;  // full 200-add chain, every lane (redundant x4)

  #define LD_T(buf, base)                                            \
    _Pragma("unroll") for (int p = 0; p < 10; ++p)                   \
        buf[p] = gtok[4 * ((base) + p) + q];
  #define GA_T(gbuf, buf)                                            \
    _Pragma("unroll") for (int p = 0; p < 10; ++p) {                 \
      c0 += (buf[p] != 0);                                           \
      gbuf[p] = table[(size_t)buf[p] * EMBED + e];                   \
    }
  #define CONSUME(gbuf)                                              \
    _Pragma("unroll") for (int p = 0; p < 10; ++p) {                 \
      acc = __fadd_rn(acc, bperm_f32(bp0, gbuf[p]));                 \
      acc = __fadd_rn(acc, bperm_f32(bp1, gbuf[p]));                 \
      acc = __fadd_rn(acc, bperm_f32(bp2, gbuf[p]));                 \
      acc = __fadd_rn(acc, bperm_f32(bp3, gbuf[p]));                 \
    }

  LD_T(tA, 0);  GA_T(g0, tA);
  LD_T(tB, 10); GA_T(g1, tB); CONSUME(g0);   // i   0.. 39
  LD_T(tA, 20); GA_T(g0, tA); CONSUME(g1);   // i  40.. 79
  LD_T(tB, 30); GA_T(g1, tB); CONSUME(g0);   // i  80..119
  LD_T(tA, 40); GA_T(g0, tA); CONSUME(g1);   // i 120..159
  CONSUME(g0);                               // i 160..199
  #undef LD_T
  #undef GA_T
  #undef CONSUME

  int cnt = c0;
  cnt += __shfl_xor(cnt, 16, 64);
  cnt += __shfl_xor(cnt, 32, 64);
  float valid = fmaxf((float)cnt, 1.0f);          // clip(mask.sum, 1.0)
  float avgv = __fdiv_rn(acc, valid);             // avg_emb[b][e], bit-exact

  // ---- cur = avg_emb @ Wc^T + bc (h = lane), FMA dot e ascending ----------
  int h = lane;
  float d = 0.0f;
  #pragma unroll
  for (int e2 = 0; e2 < EMBED; ++e2) {
    float ae = __shfl(avgv, e2, 64);              // wave-uniform source lane
    d = fmaf(ae, Wc[h * EMBED + e2], d);
  }
  float cur = __fadd_rn(d, bc[h]);

  // ---- cortex recurrence: round-7 numerics + execz fail-skip --------------
  float v = 0.0f, rfr = 0.0f;
  int ac = 0;
  #pragma unroll
  for (int t = 0; t < TICKS; ++t) {
    uint32_t nb = tf_fold(K.n0[t], K.n1[t], (uint32_t)j);
    float z = noise_from_bits(nb);
    // v = ((v * 0.98f) + cur) + noise — strict f32
    v = __fadd_rn(__fadd_rn(__fmul_rn(v, 0.98f), cur), z);
    bool cand = (__fsub_rn(v, rfr) > 0.5f);
    bool fire = false;
    if (cand) {   // divergent skip: wave with no candidates skips the hash
      uint32_t fb = tf_fold(K.f0[t], K.f1[t], (uint32_t)j);
      fire = (fb >> 31) != 0u;   // uniform >= 0.5 == MSB set
    }
    if (fire) v = 0.0f;
    rfr = __fadd_rn(__fmul_rn(rfr, 0.95f), fire ? 1.0f : 0.0f);
    ac += fire;
  }

  float s = __fdiv_rn((float)ac, 10.0f);

  // avg_spikes output (offset B*4), coalesced
  out[B_ROWS * 4 + j] = s;

  // logits = avg_spikes @ Wr^T + br — f64 butterfly over the wave's 64 h's.
  double pc[4];
  #pragma unroll
  for (int cc = 0; cc < 4; ++cc)
    pc[cc] = (double)s * (double)Wr[cc * HIDDEN + h];
  #pragma unroll
  for (int off = 32; off >= 1; off >>= 1) {
    #pragma unroll
    for (int cc = 0; cc < 4; ++cc) pc[cc] += __shfl_xor(pc[cc], off, 64);
  }
  if (lane == 0) {
    #pragma unroll
    for (int cc = 0; cc < 4; ++cc)
      out[b * 4 + cc] = (float)(pc[cc] + (double)br[cc]);
  }
}

extern "C" void kernel_launch(void* const* d_in, const int* in_sizes, int n_in,
                              void* d_out, int out_size, void* d_ws, size_t ws_size,
                              hipStream_t stream) {
  const int*   tokens = (const int*)d_in[0];
  const float* table  = (const float*)d_in[1];
  const float* Wc     = (const float*)d_in[2];
  const float* bc     = (const float*)d_in[3];
  const float* Wr     = (const float*)d_in[4];
  const float* br     = (const float*)d_in[5];
  float* out = (float*)d_out;

  // Host-side threefry key derivation (identical every call — deterministic).
  Keys K;
  for (int t = 0; t < TICKS; ++t) {
    uint32_t kt0, kt1, a0, a1;
    tf2x32(0u, 1u, 0u, (uint32_t)t, kt0, kt1);
    tf2x32(kt0, kt1, 0u, 0u, a0, a1);
    K.n0[t] = a0; K.n1[t] = a1;
    tf2x32(kt0, kt1, 0u, 1u, a0, a1);
    K.f0[t] = a0; K.f1[t] = a1;
  }

  fused_kernel<<<B_ROWS / 4, 256, 0, stream>>>(
      tokens, table, Wc, bc, Wr, br, out, K);
}